// Round 4
// baseline (2803.961 us; speedup 1.0000x reference)
//
#include <hip/hip_runtime.h>
#include <math.h>

#define EPS_GN 1e-5f

// ---------------------------------------------------------------------------
// block-wide reduce of (sum, sumsq) in double, atomicAdd into acc[0], acc[1]
// blockDim.x must be 256 (4 waves).
// ---------------------------------------------------------------------------
__device__ __forceinline__ void block_reduce_acc(double s, double s2, double* accn) {
  #pragma unroll
  for (int o = 32; o > 0; o >>= 1) {
    s  += __shfl_down(s, o, 64);
    s2 += __shfl_down(s2, o, 64);
  }
  __shared__ double red[8];
  int wv = threadIdx.x >> 6;
  if ((threadIdx.x & 63) == 0) { red[wv] = s; red[4 + wv] = s2; }
  __syncthreads();
  if (threadIdx.x == 0) {
    double ts = red[0] + red[1] + red[2] + red[3];
    double t2 = red[4] + red[5] + red[6] + red[7];
    atomicAdd(&accn[0], ts);
    atomicAdd(&accn[1], t2);
  }
}

// ---------------------------------------------------------------------------
__global__ void zero_acc_kernel(double* acc) {  // <<<1,256>>>, 4*32*2 = 256
  acc[threadIdx.x] = 0.0;
}

// ---------------------------------------------------------------------------
// BitNet ternary quantization: scale = mean(|w|) + 1e-8 ;
// q = clip(round(w/scale), -1, 1) * scale.   One block per weight tensor.
// ---------------------------------------------------------------------------
__global__ __launch_bounds__(256) void quant_kernel(
    const float* __restrict__ w1, const float* __restrict__ w2,
    const float* __restrict__ w3, const float* __restrict__ w4,
    float* __restrict__ q1, float* __restrict__ q2,
    float* __restrict__ q3, float* __restrict__ q4) {
  const float* w; float* q; int cnt;
  if      (blockIdx.x == 0) { w = w1; q = q1; cnt = 32  * 1   * 10; }
  else if (blockIdx.x == 1) { w = w2; q = q2; cnt = 64  * 32  * 8;  }
  else if (blockIdx.x == 2) { w = w3; q = q3; cnt = 128 * 64  * 8;  }
  else                      { w = w4; q = q4; cnt = 256 * 128 * 8;  }

  double s = 0.0;
  for (int i = threadIdx.x; i < cnt; i += 256) s += (double)fabsf(w[i]);
  #pragma unroll
  for (int o = 32; o > 0; o >>= 1) s += __shfl_down(s, o, 64);
  __shared__ double red[4];
  __shared__ float scale_sh;
  if ((threadIdx.x & 63) == 0) red[threadIdx.x >> 6] = s;
  __syncthreads();
  if (threadIdx.x == 0) {
    double tot = red[0] + red[1] + red[2] + red[3];
    scale_sh = (float)(tot / (double)cnt) + 1e-8f;
  }
  __syncthreads();
  float scale = scale_sh;
  for (int i = threadIdx.x; i < cnt; i += 256) {
    float r = rintf(w[i] / scale);          // round-half-even, matches jnp.round
    r = fminf(1.f, fmaxf(-1.f, r));
    q[i] = r * scale;
  }
}

// ---------------------------------------------------------------------------
// Block 1 conv: cin=1, cout=32, k=10, s=5, pad=5. 8 cout per thread, 1 l each.
// x is pre-offset to the chunk's first sample; acc_b pre-offset likewise.
// ---------------------------------------------------------------------------
__global__ __launch_bounds__(256) void conv1_kernel(
    const float* __restrict__ x, const float* __restrict__ wq,
    float* __restrict__ out, double* __restrict__ acc_b,
    int Lin, int Lout, int Pout) {
  const int CPT = 8, K = 10, S = 5;
  int n  = blockIdx.z;
  int co0 = blockIdx.y * CPT;
  int l  = blockIdx.x * 256 + threadIdx.x;

  __shared__ float wlds[CPT * K];
  if (threadIdx.x < CPT * K) wlds[threadIdx.x] = wq[co0 * K + threadIdx.x];
  __syncthreads();

  float accv[CPT];
  #pragma unroll
  for (int j = 0; j < CPT; ++j) accv[j] = 0.f;

  if (l < Lout) {
    const float* ip = x + (size_t)n * Lin;
    int base = l * S - 5;
    float win[K];
    #pragma unroll
    for (int t = 0; t < K; ++t) {
      int idx = base + t;
      win[t] = (idx >= 0 && idx < Lin) ? ip[idx] : 0.f;
    }
    #pragma unroll
    for (int j = 0; j < CPT; ++j)
      #pragma unroll
      for (int t = 0; t < K; ++t)
        accv[j] = fmaf(win[t], wlds[j * K + t], accv[j]);
    #pragma unroll
    for (int j = 0; j < CPT; ++j)
      out[((size_t)n * 32 + co0 + j) * Pout + l] = accv[j];
  }

  double s = 0.0, s2 = 0.0;
  if (l < Lout) {
    #pragma unroll
    for (int j = 0; j < CPT; ++j) { double v = accv[j]; s += v; s2 += v * v; }
  }
  block_reduce_acc(s, s2, acc_b + 2 * n);
}

// ---------------------------------------------------------------------------
// Blocks 2-4 conv: k=8, s=4, pad=4. 4 cout x 4 contiguous l per thread.
// Rows are pitched to a multiple of 4 floats so interior windows are 16B
// aligned -> float4 loads/stores.
// ---------------------------------------------------------------------------
template <int CIN, int COUT>
__global__ __launch_bounds__(256) void conv8_kernel(
    const float* __restrict__ in, const float* __restrict__ wq,
    float* __restrict__ out, double* __restrict__ acc_b,
    int Lin, int Pin, int Lout, int Pout) {
  const int K = 8, S = 4, CPT = 4, LPT = 4;
  const int WIN = (LPT - 1) * S + K;  // 20

  int n   = blockIdx.z;
  int co0 = blockIdx.y * CPT;
  int l0  = (blockIdx.x * 256 + threadIdx.x) * LPT;

  __shared__ float wlds[CPT * CIN * K];
  for (int i = threadIdx.x; i < CPT * CIN * K; i += 256)
    wlds[i] = wq[(size_t)co0 * CIN * K + i];
  __syncthreads();

  float accv[CPT][LPT];
  #pragma unroll
  for (int j = 0; j < CPT; ++j)
    #pragma unroll
    for (int r = 0; r < LPT; ++r) accv[j][r] = 0.f;

  bool any = (l0 < Lout);
  if (any) {
    const float* inb = in + (size_t)n * CIN * Pin;
    int base0 = l0 * S - 4;  // multiple of 4 floats (16B) by construction
    bool fast = (base0 >= 0) && (base0 + WIN <= Lin);
    if (fast) {
      for (int ci = 0; ci < CIN; ++ci) {
        const float4* ip4 =
            reinterpret_cast<const float4*>(inb + (size_t)ci * Pin + base0);
        float win[WIN];
        #pragma unroll
        for (int q = 0; q < WIN / 4; ++q) {
          float4 v = ip4[q];
          win[4 * q + 0] = v.x; win[4 * q + 1] = v.y;
          win[4 * q + 2] = v.z; win[4 * q + 3] = v.w;
        }
        #pragma unroll
        for (int j = 0; j < CPT; ++j) {
          const float* wp = &wlds[(j * CIN + ci) * K];
          #pragma unroll
          for (int r = 0; r < LPT; ++r)
            #pragma unroll
            for (int t = 0; t < K; ++t)
              accv[j][r] = fmaf(win[r * S + t], wp[t], accv[j][r]);
        }
      }
    } else {
      for (int ci = 0; ci < CIN; ++ci) {
        const float* ip = inb + (size_t)ci * Pin;
        float win[WIN];
        #pragma unroll
        for (int q = 0; q < WIN; ++q) {
          int idx = base0 + q;
          win[q] = (idx >= 0 && idx < Lin) ? ip[idx] : 0.f;
        }
        #pragma unroll
        for (int j = 0; j < CPT; ++j) {
          const float* wp = &wlds[(j * CIN + ci) * K];
          #pragma unroll
          for (int r = 0; r < LPT; ++r)
            #pragma unroll
            for (int t = 0; t < K; ++t)
              accv[j][r] = fmaf(win[r * S + t], wp[t], accv[j][r]);
        }
      }
    }
    if (l0 + LPT <= Lout) {
      #pragma unroll
      for (int j = 0; j < CPT; ++j) {
        float4 st = make_float4(accv[j][0], accv[j][1], accv[j][2], accv[j][3]);
        *reinterpret_cast<float4*>(out + ((size_t)n * COUT + co0 + j) * Pout + l0) = st;
      }
    } else {
      #pragma unroll
      for (int j = 0; j < CPT; ++j)
        #pragma unroll
        for (int r = 0; r < LPT; ++r)
          if (l0 + r < Lout)
            out[((size_t)n * COUT + co0 + j) * Pout + l0 + r] = accv[j][r];
    }
  }

  double s = 0.0, s2 = 0.0;
  if (any) {
    #pragma unroll
    for (int j = 0; j < CPT; ++j)
      #pragma unroll
      for (int r = 0; r < LPT; ++r)
        if (l0 + r < Lout) { double v = accv[j][r]; s += v; s2 += v * v; }
  }
  block_reduce_acc(s, s2, acc_b + 2 * n);
}

// ---------------------------------------------------------------------------
// LayerNorm over (C,L) per sample + snake activation, in place.
// grid: (ceil(L/256), C, NC)
// ---------------------------------------------------------------------------
__global__ __launch_bounds__(256) void norm_kernel(
    float* __restrict__ y, const double* __restrict__ acc_b,
    const float* __restrict__ g, const float* __restrict__ b,
    const float* __restrict__ a, const float* __restrict__ p,
    int L, int P, double invCount) {
  int n = blockIdx.z;
  int c = blockIdx.y;
  int l = blockIdx.x * 256 + threadIdx.x;
  if (l >= L) return;
  double sd  = acc_b[2 * n];
  double s2d = acc_b[2 * n + 1];
  double mu_d = sd * invCount;
  float mu  = (float)mu_d;
  float var = (float)(s2d * invCount - mu_d * mu_d);
  float rs  = rsqrtf(var + EPS_GN);
  size_t idx = ((size_t)n * gridDim.y + c) * P + l;
  float v  = y[idx];
  float z  = (v - mu) * rs * g[c] + b[c];
  float ac = a[c];
  float sv = __sinf(fmaf(ac, z, p[c]));
  y[idx] = z + sv * sv / ac;
}

// ---------------------------------------------------------------------------
// Final block: norm + snake + NCH->NHC transpose into d_out (pre-offset).
// grid: (L, 1, NC), block: 256 (=C)
// ---------------------------------------------------------------------------
__global__ __launch_bounds__(256) void norm4t_kernel(
    const float* __restrict__ y, const double* __restrict__ acc_b,
    const float* __restrict__ g, const float* __restrict__ b,
    const float* __restrict__ a, const float* __restrict__ p,
    float* __restrict__ out, int L, int P, double invCount) {
  int n = blockIdx.z;
  int l = blockIdx.x;
  int c = threadIdx.x;
  double sd  = acc_b[2 * n];
  double s2d = acc_b[2 * n + 1];
  double mu_d = sd * invCount;
  float mu  = (float)mu_d;
  float var = (float)(s2d * invCount - mu_d * mu_d);
  float rs  = rsqrtf(var + EPS_GN);
  float v  = y[((size_t)n * 256 + c) * P + l];
  float z  = (v - mu) * rs * g[c] + b[c];
  float ac = a[c];
  float sv = __sinf(fmaf(ac, z, p[c]));
  out[((size_t)n * L + l) * 256 + c] = z + sv * sv / ac;
}

// ---------------------------------------------------------------------------
extern "C" void kernel_launch(void* const* d_in, const int* in_sizes, int n_in,
                              void* d_out, int out_size, void* d_ws, size_t ws_size,
                              hipStream_t stream) {
  const float* x  = (const float*)d_in[0];
  const float* w1 = (const float*)d_in[1];
  const float* g1 = (const float*)d_in[2];
  const float* b1 = (const float*)d_in[3];
  const float* a1 = (const float*)d_in[4];
  const float* p1 = (const float*)d_in[5];
  const float* w2 = (const float*)d_in[6];
  const float* g2 = (const float*)d_in[7];
  const float* b2 = (const float*)d_in[8];
  const float* a2 = (const float*)d_in[9];
  const float* p2 = (const float*)d_in[10];
  const float* w3 = (const float*)d_in[11];
  const float* g3 = (const float*)d_in[12];
  const float* b3 = (const float*)d_in[13];
  const float* a3 = (const float*)d_in[14];
  const float* p3 = (const float*)d_in[15];
  const float* w4 = (const float*)d_in[16];
  const float* g4 = (const float*)d_in[17];
  const float* b4 = (const float*)d_in[18];
  const float* a4 = (const float*)d_in[19];
  const float* p4 = (const float*)d_in[20];
  float* out = (float*)d_out;
  char* ws = (char*)d_ws;

  const int N  = 32;
  const int L0 = 320000;
  const int L1 = 64001, P1 = 64004;
  const int L2 = 16001, P2 = 16004;
  const int L3 = 4001,  P3 = 4004;
  const int L4 = 1001,  P4 = 1004;

  // fixed workspace region: accumulators + quantized weights
  double* acc = (double*)ws;                    // 4 layers * 32 n * 2 doubles
  float* q1 = (float*)(ws + 4096);              // 320 floats
  float* q2 = (float*)(ws + 8192);              // 16384 floats
  float* q3 = (float*)(ws + 81920);             // 65536 floats
  float* q4 = (float*)(ws + 352256);            // 262144 floats
  const size_t fixedEnd = 1572864;

  // per-sample ping-pong buffer sizes (floats)
  // bufA: layer1 out (32*P1) also holds layer3 out (128*P3 = 512512, smaller)
  // bufB: layer2 out (64*P2)  also holds layer4 out (256*P4 = 257024, smaller)
  const size_t aPer = (size_t)32 * P1;          // 2,048,128 floats
  const size_t bPer = (size_t)64 * P2;          // 1,024,256 floats
  const size_t perSampleBytes = (aPer + bPer) * 4;  // ~12.3 MB

  // largest chunk of samples that fits the workspace (deterministic in ws_size)
  int NC = (ws_size > fixedEnd) ? (int)((ws_size - fixedEnd) / perSampleBytes) : 0;
  if (NC < 1) NC = 1;          // last resort; assume ws >= ~14 MB
  if (NC > N) NC = N;

  float* bufA = (float*)(ws + fixedEnd);
  float* bufB = bufA + aPer * NC;

  hipLaunchKernelGGL(zero_acc_kernel, dim3(1), dim3(256), 0, stream, acc);
  hipLaunchKernelGGL(quant_kernel, dim3(4), dim3(256), 0, stream,
                     w1, w2, w3, w4, q1, q2, q3, q4);

  for (int nb = 0; nb < N; nb += NC) {
    int nc = (N - nb < NC) ? (N - nb) : NC;
    const float* xc = x + (size_t)nb * L0;

    // block 1
    hipLaunchKernelGGL(conv1_kernel, dim3((L1 + 255) / 256, 4, nc), dim3(256), 0, stream,
                       xc, q1, bufA, acc + 0 + 2 * nb, L0, L1, P1);
    hipLaunchKernelGGL(norm_kernel, dim3((L1 + 255) / 256, 32, nc), dim3(256), 0, stream,
                       bufA, acc + 0 + 2 * nb, g1, b1, a1, p1, L1, P1,
                       1.0 / (32.0 * (double)L1));
    // block 2
    hipLaunchKernelGGL((conv8_kernel<32, 64>), dim3((L2 + 1023) / 1024, 16, nc), dim3(256), 0, stream,
                       bufA, q2, bufB, acc + 64 + 2 * nb, L1, P1, L2, P2);
    hipLaunchKernelGGL(norm_kernel, dim3((L2 + 255) / 256, 64, nc), dim3(256), 0, stream,
                       bufB, acc + 64 + 2 * nb, g2, b2, a2, p2, L2, P2,
                       1.0 / (64.0 * (double)L2));
    // block 3 (note: bufA rows now pitched P3, 128 channels -> fits in aPer)
    hipLaunchKernelGGL((conv8_kernel<64, 128>), dim3((L3 + 1023) / 1024, 32, nc), dim3(256), 0, stream,
                       bufB, q3, bufA, acc + 128 + 2 * nb, L2, P2, L3, P3);
    hipLaunchKernelGGL(norm_kernel, dim3((L3 + 255) / 256, 128, nc), dim3(256), 0, stream,
                       bufA, acc + 128 + 2 * nb, g3, b3, a3, p3, L3, P3,
                       1.0 / (128.0 * (double)L3));
    // block 4 (+ fused transpose)
    hipLaunchKernelGGL((conv8_kernel<128, 256>), dim3((L4 + 1023) / 1024, 64, nc), dim3(256), 0, stream,
                       bufA, q4, bufB, acc + 192 + 2 * nb, L3, P3, L4, P4);
    hipLaunchKernelGGL(norm4t_kernel, dim3(L4, 1, nc), dim3(256), 0, stream,
                       bufB, acc + 192 + 2 * nb, g4, b4, a4, p4,
                       out + (size_t)nb * L4 * 256, L4, P4,
                       1.0 / (256.0 * (double)L4));
  }
}

// Round 5
// 2253.536 us; speedup vs baseline: 1.2442x; 1.2442x over previous
//
#include <hip/hip_runtime.h>
#include <math.h>

#define EPS_GN 1e-5f

// workspace doubles: [0..255] = layer stats (4 layers x 32 n x {sum,sumsq}),
//                    [256..259] = per-layer sum(|w|)
#define ACC_DOUBLES 260

// ---------------------------------------------------------------------------
// block-wide reduce of (sum, sumsq) in double, atomicAdd into acc[0], acc[1]
// blockDim.x must be 256 (4 waves).
// ---------------------------------------------------------------------------
__device__ __forceinline__ void block_reduce_acc(double s, double s2, double* accn) {
  #pragma unroll
  for (int o = 32; o > 0; o >>= 1) {
    s  += __shfl_down(s, o, 64);
    s2 += __shfl_down(s2, o, 64);
  }
  __shared__ double red[8];
  int wv = threadIdx.x >> 6;
  if ((threadIdx.x & 63) == 0) { red[wv] = s; red[4 + wv] = s2; }
  __syncthreads();
  if (threadIdx.x == 0) {
    double ts = red[0] + red[1] + red[2] + red[3];
    double t2 = red[4] + red[5] + red[6] + red[7];
    atomicAdd(&accn[0], ts);
    atomicAdd(&accn[1], t2);
  }
}

// quantization scale from the accumulated |w| sum (same math as before:
// double mean -> float, + 1e-8f)
__device__ __forceinline__ float quant_scale(const double* wsum, double invCnt) {
  return (float)(wsum[0] * invCnt) + 1e-8f;
}

__device__ __forceinline__ float quant_w(float w, float scale) {
  float r = rintf(w / scale);               // round-half-even == jnp.round
  r = fminf(1.f, fmaxf(-1.f, r));
  return r * scale;
}

// ---------------------------------------------------------------------------
__global__ void zero_acc_kernel(double* acc) {  // <<<1,512>>>
  if (threadIdx.x < ACC_DOUBLES) acc[threadIdx.x] = 0.0;
}

// ---------------------------------------------------------------------------
// Parallel sum(|w|) for all 4 weight tensors. grid = (64, 4), block = 256.
// atomicAdd into wsum[layer].
// ---------------------------------------------------------------------------
__global__ __launch_bounds__(256) void wabs_kernel(
    const float* __restrict__ w1, const float* __restrict__ w2,
    const float* __restrict__ w3, const float* __restrict__ w4,
    double* __restrict__ wsum) {
  int layer = blockIdx.y;
  const float* w; int cnt;
  if      (layer == 0) { w = w1; cnt = 32  * 1   * 10; }
  else if (layer == 1) { w = w2; cnt = 64  * 32  * 8;  }
  else if (layer == 2) { w = w3; cnt = 128 * 64  * 8;  }
  else                 { w = w4; cnt = 256 * 128 * 8;  }

  double s = 0.0;
  for (int i = blockIdx.x * 256 + threadIdx.x; i < cnt; i += gridDim.x * 256)
    s += (double)fabsf(w[i]);
  #pragma unroll
  for (int o = 32; o > 0; o >>= 1) s += __shfl_down(s, o, 64);
  __shared__ double red[4];
  if ((threadIdx.x & 63) == 0) red[threadIdx.x >> 6] = s;
  __syncthreads();
  if (threadIdx.x == 0)
    atomicAdd(&wsum[layer], red[0] + red[1] + red[2] + red[3]);
}

// ---------------------------------------------------------------------------
// Block 1 conv: cin=1, cout=32, k=10, s=5, pad=5. 8 cout per thread, 1 l each.
// Weights quantized on the fly during LDS staging.
// ---------------------------------------------------------------------------
__global__ __launch_bounds__(256) void conv1_kernel(
    const float* __restrict__ x, const float* __restrict__ w,
    const double* __restrict__ wsum, double invCnt,
    float* __restrict__ out, double* __restrict__ acc_b,
    int Lin, int Lout, int Pout) {
  const int CPT = 8, K = 10, S = 5;
  int n  = blockIdx.z;
  int co0 = blockIdx.y * CPT;
  int l  = blockIdx.x * 256 + threadIdx.x;

  __shared__ float wlds[CPT * K];
  if (threadIdx.x < CPT * K) {
    float scale = quant_scale(wsum, invCnt);
    wlds[threadIdx.x] = quant_w(w[co0 * K + threadIdx.x], scale);
  }
  __syncthreads();

  float accv[CPT];
  #pragma unroll
  for (int j = 0; j < CPT; ++j) accv[j] = 0.f;

  if (l < Lout) {
    const float* ip = x + (size_t)n * Lin;
    int base = l * S - 5;
    float win[K];
    #pragma unroll
    for (int t = 0; t < K; ++t) {
      int idx = base + t;
      win[t] = (idx >= 0 && idx < Lin) ? ip[idx] : 0.f;
    }
    #pragma unroll
    for (int j = 0; j < CPT; ++j)
      #pragma unroll
      for (int t = 0; t < K; ++t)
        accv[j] = fmaf(win[t], wlds[j * K + t], accv[j]);
    #pragma unroll
    for (int j = 0; j < CPT; ++j)
      out[((size_t)n * 32 + co0 + j) * Pout + l] = accv[j];
  }

  double s = 0.0, s2 = 0.0;
  if (l < Lout) {
    #pragma unroll
    for (int j = 0; j < CPT; ++j) { double v = accv[j]; s += v; s2 += v * v; }
  }
  block_reduce_acc(s, s2, acc_b + 2 * n);
}

// ---------------------------------------------------------------------------
// Blocks 2-4 conv: k=8, s=4, pad=4. 4 cout x 4 contiguous l per thread.
// Rows pitched to a multiple of 4 floats -> float4 loads/stores.
// Weights quantized on the fly during LDS staging.
// ---------------------------------------------------------------------------
template <int CIN, int COUT>
__global__ __launch_bounds__(256) void conv8_kernel(
    const float* __restrict__ in, const float* __restrict__ w,
    const double* __restrict__ wsum, double invCnt,
    float* __restrict__ out, double* __restrict__ acc_b,
    int Lin, int Pin, int Lout, int Pout) {
  const int K = 8, S = 4, CPT = 4, LPT = 4;
  const int WIN = (LPT - 1) * S + K;  // 20

  int n   = blockIdx.z;
  int co0 = blockIdx.y * CPT;
  int l0  = (blockIdx.x * 256 + threadIdx.x) * LPT;

  __shared__ float wlds[CPT * CIN * K];
  {
    float scale = quant_scale(wsum, invCnt);
    for (int i = threadIdx.x; i < CPT * CIN * K; i += 256)
      wlds[i] = quant_w(w[(size_t)co0 * CIN * K + i], scale);
  }
  __syncthreads();

  float accv[CPT][LPT];
  #pragma unroll
  for (int j = 0; j < CPT; ++j)
    #pragma unroll
    for (int r = 0; r < LPT; ++r) accv[j][r] = 0.f;

  bool any = (l0 < Lout);
  if (any) {
    const float* inb = in + (size_t)n * CIN * Pin;
    int base0 = l0 * S - 4;  // multiple of 4 floats (16B) by construction
    bool fast = (base0 >= 0) && (base0 + WIN <= Lin);
    if (fast) {
      for (int ci = 0; ci < CIN; ++ci) {
        const float4* ip4 =
            reinterpret_cast<const float4*>(inb + (size_t)ci * Pin + base0);
        float win[WIN];
        #pragma unroll
        for (int q = 0; q < WIN / 4; ++q) {
          float4 v = ip4[q];
          win[4 * q + 0] = v.x; win[4 * q + 1] = v.y;
          win[4 * q + 2] = v.z; win[4 * q + 3] = v.w;
        }
        #pragma unroll
        for (int j = 0; j < CPT; ++j) {
          const float* wp = &wlds[(j * CIN + ci) * K];
          #pragma unroll
          for (int r = 0; r < LPT; ++r)
            #pragma unroll
            for (int t = 0; t < K; ++t)
              accv[j][r] = fmaf(win[r * S + t], wp[t], accv[j][r]);
        }
      }
    } else {
      for (int ci = 0; ci < CIN; ++ci) {
        const float* ip = inb + (size_t)ci * Pin;
        float win[WIN];
        #pragma unroll
        for (int q = 0; q < WIN; ++q) {
          int idx = base0 + q;
          win[q] = (idx >= 0 && idx < Lin) ? ip[idx] : 0.f;
        }
        #pragma unroll
        for (int j = 0; j < CPT; ++j) {
          const float* wp = &wlds[(j * CIN + ci) * K];
          #pragma unroll
          for (int r = 0; r < LPT; ++r)
            #pragma unroll
            for (int t = 0; t < K; ++t)
              accv[j][r] = fmaf(win[r * S + t], wp[t], accv[j][r]);
        }
      }
    }
    if (l0 + LPT <= Lout) {
      #pragma unroll
      for (int j = 0; j < CPT; ++j) {
        float4 st = make_float4(accv[j][0], accv[j][1], accv[j][2], accv[j][3]);
        *reinterpret_cast<float4*>(out + ((size_t)n * COUT + co0 + j) * Pout + l0) = st;
      }
    } else {
      #pragma unroll
      for (int j = 0; j < CPT; ++j)
        #pragma unroll
        for (int r = 0; r < LPT; ++r)
          if (l0 + r < Lout)
            out[((size_t)n * COUT + co0 + j) * Pout + l0 + r] = accv[j][r];
    }
  }

  double s = 0.0, s2 = 0.0;
  if (any) {
    #pragma unroll
    for (int j = 0; j < CPT; ++j)
      #pragma unroll
      for (int r = 0; r < LPT; ++r)
        if (l0 + r < Lout) { double v = accv[j][r]; s += v; s2 += v * v; }
  }
  block_reduce_acc(s, s2, acc_b + 2 * n);
}

// ---------------------------------------------------------------------------
// LayerNorm over (C,L) per sample + snake activation, in place.
// grid: (ceil(L/256), C, NC)
// ---------------------------------------------------------------------------
__global__ __launch_bounds__(256) void norm_kernel(
    float* __restrict__ y, const double* __restrict__ acc_b,
    const float* __restrict__ g, const float* __restrict__ b,
    const float* __restrict__ a, const float* __restrict__ p,
    int L, int P, double invCount) {
  int n = blockIdx.z;
  int c = blockIdx.y;
  int l = blockIdx.x * 256 + threadIdx.x;
  if (l >= L) return;
  double sd  = acc_b[2 * n];
  double s2d = acc_b[2 * n + 1];
  double mu_d = sd * invCount;
  float mu  = (float)mu_d;
  float var = (float)(s2d * invCount - mu_d * mu_d);
  float rs  = rsqrtf(var + EPS_GN);
  size_t idx = ((size_t)n * gridDim.y + c) * P + l;
  float v  = y[idx];
  float z  = (v - mu) * rs * g[c] + b[c];
  float ac = a[c];
  float sv = __sinf(fmaf(ac, z, p[c]));
  y[idx] = z + sv * sv / ac;
}

// ---------------------------------------------------------------------------
// Final block: norm + snake + NCH->NHC transpose into d_out (pre-offset).
// grid: (L, 1, NC), block: 256 (=C)
// ---------------------------------------------------------------------------
__global__ __launch_bounds__(256) void norm4t_kernel(
    const float* __restrict__ y, const double* __restrict__ acc_b,
    const float* __restrict__ g, const float* __restrict__ b,
    const float* __restrict__ a, const float* __restrict__ p,
    float* __restrict__ out, int L, int P, double invCount) {
  int n = blockIdx.z;
  int l = blockIdx.x;
  int c = threadIdx.x;
  double sd  = acc_b[2 * n];
  double s2d = acc_b[2 * n + 1];
  double mu_d = sd * invCount;
  float mu  = (float)mu_d;
  float var = (float)(s2d * invCount - mu_d * mu_d);
  float rs  = rsqrtf(var + EPS_GN);
  float v  = y[((size_t)n * 256 + c) * P + l];
  float z  = (v - mu) * rs * g[c] + b[c];
  float ac = a[c];
  float sv = __sinf(fmaf(ac, z, p[c]));
  out[((size_t)n * L + l) * 256 + c] = z + sv * sv / ac;
}

// ---------------------------------------------------------------------------
extern "C" void kernel_launch(void* const* d_in, const int* in_sizes, int n_in,
                              void* d_out, int out_size, void* d_ws, size_t ws_size,
                              hipStream_t stream) {
  const float* x  = (const float*)d_in[0];
  const float* w1 = (const float*)d_in[1];
  const float* g1 = (const float*)d_in[2];
  const float* b1 = (const float*)d_in[3];
  const float* a1 = (const float*)d_in[4];
  const float* p1 = (const float*)d_in[5];
  const float* w2 = (const float*)d_in[6];
  const float* g2 = (const float*)d_in[7];
  const float* b2 = (const float*)d_in[8];
  const float* a2 = (const float*)d_in[9];
  const float* p2 = (const float*)d_in[10];
  const float* w3 = (const float*)d_in[11];
  const float* g3 = (const float*)d_in[12];
  const float* b3 = (const float*)d_in[13];
  const float* a3 = (const float*)d_in[14];
  const float* p3 = (const float*)d_in[15];
  const float* w4 = (const float*)d_in[16];
  const float* g4 = (const float*)d_in[17];
  const float* b4 = (const float*)d_in[18];
  const float* a4 = (const float*)d_in[19];
  const float* p4 = (const float*)d_in[20];
  float* out = (float*)d_out;
  char* ws = (char*)d_ws;

  const int N  = 32;
  const int L0 = 320000;
  const int L1 = 64001, P1 = 64004;
  const int L2 = 16001, P2 = 16004;
  const int L3 = 4001,  P3 = 4004;
  const int L4 = 1001,  P4 = 1004;

  const double ic1 = 1.0 / (32.0  * 1.0   * 10.0);
  const double ic2 = 1.0 / (64.0  * 32.0  * 8.0);
  const double ic3 = 1.0 / (128.0 * 64.0  * 8.0);
  const double ic4 = 1.0 / (256.0 * 128.0 * 8.0);

  // fixed workspace region: stats accumulators + weight-abs sums
  double* acc  = (double*)ws;        // 256 doubles
  double* wsum = acc + 256;          // 4 doubles
  const size_t fixedEnd = 4096;

  // per-sample ping-pong buffer sizes (floats)
  const size_t aPer = (size_t)32 * P1;          // layer1 out (>= layer3 out)
  const size_t bPer = (size_t)64 * P2;          // layer2 out (>= layer4 out)
  const size_t perSampleBytes = (aPer + bPer) * 4;  // ~12.3 MB

  int NC = (ws_size > fixedEnd) ? (int)((ws_size - fixedEnd) / perSampleBytes) : 0;
  if (NC < 1) NC = 1;
  if (NC > N) NC = N;

  float* bufA = (float*)(ws + fixedEnd);
  float* bufB = bufA + aPer * NC;

  hipLaunchKernelGGL(zero_acc_kernel, dim3(1), dim3(512), 0, stream, acc);
  hipLaunchKernelGGL(wabs_kernel, dim3(64, 4), dim3(256), 0, stream,
                     w1, w2, w3, w4, wsum);

  for (int nb = 0; nb < N; nb += NC) {
    int nc = (N - nb < NC) ? (N - nb) : NC;
    const float* xc = x + (size_t)nb * L0;

    // block 1
    hipLaunchKernelGGL(conv1_kernel, dim3((L1 + 255) / 256, 4, nc), dim3(256), 0, stream,
                       xc, w1, wsum + 0, ic1, bufA, acc + 0 + 2 * nb, L0, L1, P1);
    hipLaunchKernelGGL(norm_kernel, dim3((L1 + 255) / 256, 32, nc), dim3(256), 0, stream,
                       bufA, acc + 0 + 2 * nb, g1, b1, a1, p1, L1, P1,
                       1.0 / (32.0 * (double)L1));
    // block 2
    hipLaunchKernelGGL((conv8_kernel<32, 64>), dim3((L2 + 1023) / 1024, 16, nc), dim3(256), 0, stream,
                       bufA, w2, wsum + 1, ic2, bufB, acc + 64 + 2 * nb, L1, P1, L2, P2);
    hipLaunchKernelGGL(norm_kernel, dim3((L2 + 255) / 256, 64, nc), dim3(256), 0, stream,
                       bufB, acc + 64 + 2 * nb, g2, b2, a2, p2, L2, P2,
                       1.0 / (64.0 * (double)L2));
    // block 3
    hipLaunchKernelGGL((conv8_kernel<64, 128>), dim3((L3 + 1023) / 1024, 32, nc), dim3(256), 0, stream,
                       bufB, w3, wsum + 2, ic3, bufA, acc + 128 + 2 * nb, L2, P2, L3, P3);
    hipLaunchKernelGGL(norm_kernel, dim3((L3 + 255) / 256, 128, nc), dim3(256), 0, stream,
                       bufA, acc + 128 + 2 * nb, g3, b3, a3, p3, L3, P3,
                       1.0 / (128.0 * (double)L3));
    // block 4 (+ fused transpose)
    hipLaunchKernelGGL((conv8_kernel<128, 256>), dim3((L4 + 1023) / 1024, 64, nc), dim3(256), 0, stream,
                       bufA, w4, wsum + 3, ic4, bufB, acc + 192 + 2 * nb, L3, P3, L4, P4);
    hipLaunchKernelGGL(norm4t_kernel, dim3(L4, 1, nc), dim3(256), 0, stream,
                       bufB, acc + 192 + 2 * nb, g4, b4, a4, p4,
                       out + (size_t)nb * L4 * 256, L4, P4,
                       1.0 / (256.0 * (double)L4));
  }
}

// Round 6
// 2058.952 us; speedup vs baseline: 1.3618x; 1.0945x over previous
//
#include <hip/hip_runtime.h>
#include <math.h>

#define EPS_GN 1e-5f
#define ACC_DOUBLES 260

// ---------------------------------------------------------------------------
__device__ __forceinline__ void block_reduce_acc(double s, double s2, double* accn) {
  #pragma unroll
  for (int o = 32; o > 0; o >>= 1) {
    s  += __shfl_down(s, o, 64);
    s2 += __shfl_down(s2, o, 64);
  }
  __shared__ double red[8];
  int wv = threadIdx.x >> 6;
  if ((threadIdx.x & 63) == 0) { red[wv] = s; red[4 + wv] = s2; }
  __syncthreads();
  if (threadIdx.x == 0) {
    double ts = red[0] + red[1] + red[2] + red[3];
    double t2 = red[4] + red[5] + red[6] + red[7];
    atomicAdd(&accn[0], ts);
    atomicAdd(&accn[1], t2);
  }
}

__device__ __forceinline__ float quant_scale(const double* wsum, double invCnt) {
  return (float)(wsum[0] * invCnt) + 1e-8f;
}

__device__ __forceinline__ float quant_w(float w, float scale) {
  float r = rintf(w / scale);               // round-half-even == jnp.round
  r = fminf(1.f, fmaxf(-1.f, r));
  return r * scale;
}

// ---------------------------------------------------------------------------
__global__ void zero_acc_kernel(double* acc) {  // <<<1,512>>>
  if (threadIdx.x < ACC_DOUBLES) acc[threadIdx.x] = 0.0;
}

// ---------------------------------------------------------------------------
// Parallel sum(|w|), grid = (64, 4), block = 256, atomicAdd per layer.
// ---------------------------------------------------------------------------
__global__ __launch_bounds__(256) void wabs_kernel(
    const float* __restrict__ w1, const float* __restrict__ w2,
    const float* __restrict__ w3, const float* __restrict__ w4,
    double* __restrict__ wsum) {
  int layer = blockIdx.y;
  const float* w; int cnt;
  if      (layer == 0) { w = w1; cnt = 32  * 1   * 10; }
  else if (layer == 1) { w = w2; cnt = 64  * 32  * 8;  }
  else if (layer == 2) { w = w3; cnt = 128 * 64  * 8;  }
  else                 { w = w4; cnt = 256 * 128 * 8;  }

  double s = 0.0;
  for (int i = blockIdx.x * 256 + threadIdx.x; i < cnt; i += gridDim.x * 256)
    s += (double)fabsf(w[i]);
  #pragma unroll
  for (int o = 32; o > 0; o >>= 1) s += __shfl_down(s, o, 64);
  __shared__ double red[4];
  if ((threadIdx.x & 63) == 0) red[threadIdx.x >> 6] = s;
  __syncthreads();
  if (threadIdx.x == 0)
    atomicAdd(&wsum[layer], red[0] + red[1] + red[2] + red[3]);
}

// ---------------------------------------------------------------------------
// Block 1 conv: cin=1, cout=32, k=10, s=5, pad=5. 8 cout per thread, 1 l each.
// ---------------------------------------------------------------------------
__global__ __launch_bounds__(256) void conv1_kernel(
    const float* __restrict__ x, const float* __restrict__ w,
    const double* __restrict__ wsum, double invCnt,
    float* __restrict__ out, double* __restrict__ acc_b,
    int Lin, int Lout, int Pout) {
  const int CPT = 8, K = 10, S = 5;
  int n  = blockIdx.z;
  int co0 = blockIdx.y * CPT;
  int l  = blockIdx.x * 256 + threadIdx.x;

  __shared__ float wlds[CPT * K];
  if (threadIdx.x < CPT * K) {
    float scale = quant_scale(wsum, invCnt);
    wlds[threadIdx.x] = quant_w(w[co0 * K + threadIdx.x], scale);
  }
  __syncthreads();

  float accv[CPT];
  #pragma unroll
  for (int j = 0; j < CPT; ++j) accv[j] = 0.f;

  if (l < Lout) {
    const float* ip = x + (size_t)n * Lin;
    int base = l * S - 5;
    float win[K];
    #pragma unroll
    for (int t = 0; t < K; ++t) {
      int idx = base + t;
      win[t] = (idx >= 0 && idx < Lin) ? ip[idx] : 0.f;
    }
    #pragma unroll
    for (int j = 0; j < CPT; ++j)
      #pragma unroll
      for (int t = 0; t < K; ++t)
        accv[j] = fmaf(win[t], wlds[j * K + t], accv[j]);
    #pragma unroll
    for (int j = 0; j < CPT; ++j)
      out[((size_t)n * 32 + co0 + j) * Pout + l] = accv[j];
  }

  double s = 0.0, s2 = 0.0;
  if (l < Lout) {
    #pragma unroll
    for (int j = 0; j < CPT; ++j) { double v = accv[j]; s += v; s2 += v * v; }
  }
  block_reduce_acc(s, s2, acc_b + 2 * n);
}

// ---------------------------------------------------------------------------
// Blocks 2-4 conv: k=8, s=4, pad=4. CPT=8 cout x LPT=4 contiguous l / thread.
// CPT=8 halves the per-cout-group input re-read (vs 4) and doubles FMA per
// staged window. Rows pitched to 4 floats -> float4 loads/stores.
// ---------------------------------------------------------------------------
template <int CIN, int COUT>
__global__ __launch_bounds__(256) void conv8_kernel(
    const float* __restrict__ in, const float* __restrict__ w,
    const double* __restrict__ wsum, double invCnt,
    float* __restrict__ out, double* __restrict__ acc_b,
    int Lin, int Pin, int Lout, int Pout) {
  const int K = 8, S = 4, CPT = 8, LPT = 4;
  const int WIN = (LPT - 1) * S + K;  // 20

  int n   = blockIdx.z;
  int co0 = blockIdx.y * CPT;
  int l0  = (blockIdx.x * 256 + threadIdx.x) * LPT;

  __shared__ float wlds[CPT * CIN * K];
  {
    float scale = quant_scale(wsum, invCnt);
    for (int i = threadIdx.x; i < CPT * CIN * K; i += 256)
      wlds[i] = quant_w(w[(size_t)co0 * CIN * K + i], scale);
  }
  __syncthreads();

  float accv[CPT][LPT];
  #pragma unroll
  for (int j = 0; j < CPT; ++j)
    #pragma unroll
    for (int r = 0; r < LPT; ++r) accv[j][r] = 0.f;

  bool any = (l0 < Lout);
  if (any) {
    const float* inb = in + (size_t)n * CIN * Pin;
    int base0 = l0 * S - 4;  // multiple of 4 floats (16B) by construction
    bool fast = (base0 >= 0) && (base0 + WIN <= Lin);
    if (fast) {
      for (int ci = 0; ci < CIN; ++ci) {
        const float4* ip4 =
            reinterpret_cast<const float4*>(inb + (size_t)ci * Pin + base0);
        float win[WIN];
        #pragma unroll
        for (int q = 0; q < WIN / 4; ++q) {
          float4 v = ip4[q];
          win[4 * q + 0] = v.x; win[4 * q + 1] = v.y;
          win[4 * q + 2] = v.z; win[4 * q + 3] = v.w;
        }
        #pragma unroll
        for (int j = 0; j < CPT; ++j) {
          const float* wp = &wlds[(j * CIN + ci) * K];
          #pragma unroll
          for (int r = 0; r < LPT; ++r)
            #pragma unroll
            for (int t = 0; t < K; ++t)
              accv[j][r] = fmaf(win[r * S + t], wp[t], accv[j][r]);
        }
      }
    } else {
      for (int ci = 0; ci < CIN; ++ci) {
        const float* ip = inb + (size_t)ci * Pin;
        float win[WIN];
        #pragma unroll
        for (int q = 0; q < WIN; ++q) {
          int idx = base0 + q;
          win[q] = (idx >= 0 && idx < Lin) ? ip[idx] : 0.f;
        }
        #pragma unroll
        for (int j = 0; j < CPT; ++j) {
          const float* wp = &wlds[(j * CIN + ci) * K];
          #pragma unroll
          for (int r = 0; r < LPT; ++r)
            #pragma unroll
            for (int t = 0; t < K; ++t)
              accv[j][r] = fmaf(win[r * S + t], wp[t], accv[j][r]);
        }
      }
    }
    if (l0 + LPT <= Lout) {
      #pragma unroll
      for (int j = 0; j < CPT; ++j) {
        float4 st = make_float4(accv[j][0], accv[j][1], accv[j][2], accv[j][3]);
        *reinterpret_cast<float4*>(out + ((size_t)n * COUT + co0 + j) * Pout + l0) = st;
      }
    } else {
      #pragma unroll
      for (int j = 0; j < CPT; ++j)
        #pragma unroll
        for (int r = 0; r < LPT; ++r)
          if (l0 + r < Lout)
            out[((size_t)n * COUT + co0 + j) * Pout + l0 + r] = accv[j][r];
    }
  }

  double s = 0.0, s2 = 0.0;
  if (any) {
    #pragma unroll
    for (int j = 0; j < CPT; ++j)
      #pragma unroll
      for (int r = 0; r < LPT; ++r)
        if (l0 + r < Lout) { double v = accv[j][r]; s += v; s2 += v * v; }
  }
  block_reduce_acc(s, s2, acc_b + 2 * n);
}

// ---------------------------------------------------------------------------
// LayerNorm + snake, in place, float4-vectorized (4 l per thread).
// grid: (ceil(L/1024), C, NC)
// ---------------------------------------------------------------------------
__global__ __launch_bounds__(256) void norm_kernel(
    float* __restrict__ y, const double* __restrict__ acc_b,
    const float* __restrict__ g, const float* __restrict__ b,
    const float* __restrict__ a, const float* __restrict__ p,
    int L, int P, double invCount) {
  int n = blockIdx.z;
  int c = blockIdx.y;
  int l0 = (blockIdx.x * 256 + threadIdx.x) * 4;
  if (l0 >= L) return;
  double sd  = acc_b[2 * n];
  double s2d = acc_b[2 * n + 1];
  double mu_d = sd * invCount;
  float mu  = (float)mu_d;
  float var = (float)(s2d * invCount - mu_d * mu_d);
  float rs  = rsqrtf(var + EPS_GN);
  float gc = g[c], bc = b[c], ac = a[c], pc = p[c];
  float grs = rs * gc;
  size_t base = ((size_t)n * gridDim.y + c) * P;
  if (l0 + 4 <= L) {
    float4 v = *reinterpret_cast<const float4*>(y + base + l0);
    float4 o;
    {
      float z = (v.x - mu) * grs + bc; float sv = __sinf(fmaf(ac, z, pc)); o.x = z + sv * sv / ac;
    }{
      float z = (v.y - mu) * grs + bc; float sv = __sinf(fmaf(ac, z, pc)); o.y = z + sv * sv / ac;
    }{
      float z = (v.z - mu) * grs + bc; float sv = __sinf(fmaf(ac, z, pc)); o.z = z + sv * sv / ac;
    }{
      float z = (v.w - mu) * grs + bc; float sv = __sinf(fmaf(ac, z, pc)); o.w = z + sv * sv / ac;
    }
    *reinterpret_cast<float4*>(y + base + l0) = o;
  } else {
    for (int r = 0; r < 4 && l0 + r < L; ++r) {
      float v = y[base + l0 + r];
      float z = (v - mu) * grs + bc;
      float sv = __sinf(fmaf(ac, z, pc));
      y[base + l0 + r] = z + sv * sv / ac;
    }
  }
}

// ---------------------------------------------------------------------------
// Final block: norm + snake + NCH->NHC transpose into d_out (pre-offset).
// grid: (L, 1, NC), block: 256 (=C)
// ---------------------------------------------------------------------------
__global__ __launch_bounds__(256) void norm4t_kernel(
    const float* __restrict__ y, const double* __restrict__ acc_b,
    const float* __restrict__ g, const float* __restrict__ b,
    const float* __restrict__ a, const float* __restrict__ p,
    float* __restrict__ out, int L, int P, double invCount) {
  int n = blockIdx.z;
  int l = blockIdx.x;
  int c = threadIdx.x;
  double sd  = acc_b[2 * n];
  double s2d = acc_b[2 * n + 1];
  double mu_d = sd * invCount;
  float mu  = (float)mu_d;
  float var = (float)(s2d * invCount - mu_d * mu_d);
  float rs  = rsqrtf(var + EPS_GN);
  float v  = y[((size_t)n * 256 + c) * P + l];
  float z  = (v - mu) * rs * g[c] + b[c];
  float ac = a[c];
  float sv = __sinf(fmaf(ac, z, p[c]));
  out[((size_t)n * L + l) * 256 + c] = z + sv * sv / ac;
}

// ---------------------------------------------------------------------------
extern "C" void kernel_launch(void* const* d_in, const int* in_sizes, int n_in,
                              void* d_out, int out_size, void* d_ws, size_t ws_size,
                              hipStream_t stream) {
  const float* x  = (const float*)d_in[0];
  const float* w1 = (const float*)d_in[1];
  const float* g1 = (const float*)d_in[2];
  const float* b1 = (const float*)d_in[3];
  const float* a1 = (const float*)d_in[4];
  const float* p1 = (const float*)d_in[5];
  const float* w2 = (const float*)d_in[6];
  const float* g2 = (const float*)d_in[7];
  const float* b2 = (const float*)d_in[8];
  const float* a2 = (const float*)d_in[9];
  const float* p2 = (const float*)d_in[10];
  const float* w3 = (const float*)d_in[11];
  const float* g3 = (const float*)d_in[12];
  const float* b3 = (const float*)d_in[13];
  const float* a3 = (const float*)d_in[14];
  const float* p3 = (const float*)d_in[15];
  const float* w4 = (const float*)d_in[16];
  const float* g4 = (const float*)d_in[17];
  const float* b4 = (const float*)d_in[18];
  const float* a4 = (const float*)d_in[19];
  const float* p4 = (const float*)d_in[20];
  float* out = (float*)d_out;
  char* ws = (char*)d_ws;

  const int N  = 32;
  const int L0 = 320000;
  const int L1 = 64001, P1 = 64004;
  const int L2 = 16001, P2 = 16004;
  const int L3 = 4001,  P3 = 4004;
  const int L4 = 1001,  P4 = 1004;

  const double ic1 = 1.0 / (32.0  * 1.0   * 10.0);
  const double ic2 = 1.0 / (64.0  * 32.0  * 8.0);
  const double ic3 = 1.0 / (128.0 * 64.0  * 8.0);
  const double ic4 = 1.0 / (256.0 * 128.0 * 8.0);

  double* acc  = (double*)ws;        // 256 doubles: stats
  double* wsum = acc + 256;          // 4 doubles: sum|w|
  const size_t fixedEnd = 4096;

  const size_t aPer = (size_t)32 * P1;          // layer1 out (>= layer3 out)
  const size_t bPer = (size_t)64 * P2;          // layer2 out (>= layer4 out)
  const size_t perSampleBytes = (aPer + bPer) * 4;

  int NC = (ws_size > fixedEnd) ? (int)((ws_size - fixedEnd) / perSampleBytes) : 0;
  if (NC < 1) NC = 1;
  if (NC > N) NC = N;

  float* bufA = (float*)(ws + fixedEnd);
  float* bufB = bufA + aPer * NC;

  hipLaunchKernelGGL(zero_acc_kernel, dim3(1), dim3(512), 0, stream, acc);
  hipLaunchKernelGGL(wabs_kernel, dim3(64, 4), dim3(256), 0, stream,
                     w1, w2, w3, w4, wsum);

  for (int nb = 0; nb < N; nb += NC) {
    int nc = (N - nb < NC) ? (N - nb) : NC;
    const float* xc = x + (size_t)nb * L0;

    // block 1
    hipLaunchKernelGGL(conv1_kernel, dim3((L1 + 255) / 256, 4, nc), dim3(256), 0, stream,
                       xc, w1, wsum + 0, ic1, bufA, acc + 0 + 2 * nb, L0, L1, P1);
    hipLaunchKernelGGL(norm_kernel, dim3((L1 + 1023) / 1024, 32, nc), dim3(256), 0, stream,
                       bufA, acc + 0 + 2 * nb, g1, b1, a1, p1, L1, P1,
                       1.0 / (32.0 * (double)L1));
    // block 2  (grid.y = 64/8)
    hipLaunchKernelGGL((conv8_kernel<32, 64>), dim3((L2 + 1023) / 1024, 8, nc), dim3(256), 0, stream,
                       bufA, w2, wsum + 1, ic2, bufB, acc + 64 + 2 * nb, L1, P1, L2, P2);
    hipLaunchKernelGGL(norm_kernel, dim3((L2 + 1023) / 1024, 64, nc), dim3(256), 0, stream,
                       bufB, acc + 64 + 2 * nb, g2, b2, a2, p2, L2, P2,
                       1.0 / (64.0 * (double)L2));
    // block 3  (grid.y = 128/8)
    hipLaunchKernelGGL((conv8_kernel<64, 128>), dim3((L3 + 1023) / 1024, 16, nc), dim3(256), 0, stream,
                       bufB, w3, wsum + 2, ic3, bufA, acc + 128 + 2 * nb, L2, P2, L3, P3);
    hipLaunchKernelGGL(norm_kernel, dim3((L3 + 1023) / 1024, 128, nc), dim3(256), 0, stream,
                       bufA, acc + 128 + 2 * nb, g3, b3, a3, p3, L3, P3,
                       1.0 / (128.0 * (double)L3));
    // block 4 (+ fused transpose)  (grid.y = 256/8)
    hipLaunchKernelGGL((conv8_kernel<128, 256>), dim3((L4 + 1023) / 1024, 32, nc), dim3(256), 0, stream,
                       bufA, w4, wsum + 3, ic4, bufB, acc + 192 + 2 * nb, L3, P3, L4, P4);
    hipLaunchKernelGGL(norm4t_kernel, dim3(L4, 1, nc), dim3(256), 0, stream,
                       bufB, acc + 192 + 2 * nb, g4, b4, a4, p4,
                       out + (size_t)nb * L4 * 256, L4, P4,
                       1.0 / (256.0 * (double)L4));
  }
}